// Round 2
// baseline (399.398 us; speedup 1.0000x reference)
//
#include <hip/hip_runtime.h>
#include <hip/hip_bf16.h>

#define NTOK 1024
#define EMB  1024
#define NH   16
#define HD   64
#define NS   128

// ---------------------------------------------------------------------------
// C[M,N] = A[M,K] * B[N,K]^T + bias[N]    (all row-major, M=N=K=1024), A fp32
// 64x64 tile, BK=16, 256 threads, 4x4 per thread.
// ---------------------------------------------------------------------------
__global__ __launch_bounds__(256) void gemm_nt(const float* __restrict__ A,
                                               const float* __restrict__ B,
                                               const float* __restrict__ bias,
                                               float* __restrict__ C) {
  const int K = 1024;
  __shared__ float As[64][17];
  __shared__ float Bs[64][17];

  const int t  = threadIdx.x;
  const int tx = t & 15;
  const int ty = t >> 4;
  const int row0 = blockIdx.y * 64;
  const int col0 = blockIdx.x * 64;

  const int lr = t >> 2;        // 0..63
  const int lc = (t & 3) * 4;   // 0,4,8,12

  float acc[4][4] = {};

  for (int k0 = 0; k0 < K; k0 += 16) {
    const float4 av = *(const float4*)&A[(size_t)(row0 + lr) * K + k0 + lc];
    const float4 bv = *(const float4*)&B[(size_t)(col0 + lr) * K + k0 + lc];
    As[lr][lc + 0] = av.x; As[lr][lc + 1] = av.y;
    As[lr][lc + 2] = av.z; As[lr][lc + 3] = av.w;
    Bs[lr][lc + 0] = bv.x; Bs[lr][lc + 1] = bv.y;
    Bs[lr][lc + 2] = bv.z; Bs[lr][lc + 3] = bv.w;
    __syncthreads();
#pragma unroll
    for (int kk = 0; kk < 16; kk++) {
      float a[4], b[4];
#pragma unroll
      for (int i = 0; i < 4; i++) a[i] = As[ty * 4 + i][kk];
#pragma unroll
      for (int j = 0; j < 4; j++) b[j] = Bs[tx * 4 + j][kk];
#pragma unroll
      for (int i = 0; i < 4; i++)
#pragma unroll
        for (int j = 0; j < 4; j++) acc[i][j] += a[i] * b[j];
    }
    __syncthreads();
  }

#pragma unroll
  for (int i = 0; i < 4; i++) {
    const int r = row0 + ty * 4 + i;
#pragma unroll
    for (int j = 0; j < 4; j++) {
      const int c = col0 + tx * 4 + j;
      C[(size_t)r * 1024 + c] = acc[i][j] + bias[c];
    }
  }
}

// ---------------------------------------------------------------------------
// Same GEMM but A is bf16 (the attention output O).
// ---------------------------------------------------------------------------
__global__ __launch_bounds__(256) void gemm_nt_abf16(const __hip_bfloat16* __restrict__ A,
                                                     const float* __restrict__ B,
                                                     const float* __restrict__ bias,
                                                     float* __restrict__ C) {
  const int K = 1024;
  __shared__ float As[64][17];
  __shared__ float Bs[64][17];

  const int t  = threadIdx.x;
  const int tx = t & 15;
  const int ty = t >> 4;
  const int row0 = blockIdx.y * 64;
  const int col0 = blockIdx.x * 64;

  const int lr = t >> 2;
  const int lc = (t & 3) * 4;

  float acc[4][4] = {};

  for (int k0 = 0; k0 < K; k0 += 16) {
    const ushort4 av = *(const ushort4*)&A[(size_t)(row0 + lr) * K + k0 + lc];
    const float4  bv = *(const float4*)&B[(size_t)(col0 + lr) * K + k0 + lc];
    As[lr][lc + 0] = __bfloat162float(*(const __hip_bfloat16*)&av.x);
    As[lr][lc + 1] = __bfloat162float(*(const __hip_bfloat16*)&av.y);
    As[lr][lc + 2] = __bfloat162float(*(const __hip_bfloat16*)&av.z);
    As[lr][lc + 3] = __bfloat162float(*(const __hip_bfloat16*)&av.w);
    Bs[lr][lc + 0] = bv.x; Bs[lr][lc + 1] = bv.y;
    Bs[lr][lc + 2] = bv.z; Bs[lr][lc + 3] = bv.w;
    __syncthreads();
#pragma unroll
    for (int kk = 0; kk < 16; kk++) {
      float a[4], b[4];
#pragma unroll
      for (int i = 0; i < 4; i++) a[i] = As[ty * 4 + i][kk];
#pragma unroll
      for (int j = 0; j < 4; j++) b[j] = Bs[tx * 4 + j][kk];
#pragma unroll
      for (int i = 0; i < 4; i++)
#pragma unroll
        for (int j = 0; j < 4; j++) acc[i][j] += a[i] * b[j];
    }
    __syncthreads();
  }

#pragma unroll
  for (int i = 0; i < 4; i++) {
    const int r = row0 + ty * 4 + i;
#pragma unroll
    for (int j = 0; j < 4; j++) {
      const int c = col0 + tx * 4 + j;
      C[(size_t)r * 1024 + c] = acc[i][j] + bias[c];
    }
  }
}

// ---------------------------------------------------------------------------
// Per-token bitonic sort of the 128 sample indices -> sorted u16 cols.
// One 128-thread block per token. (dup flags recomputed in attn.)
// ---------------------------------------------------------------------------
__global__ __launch_bounds__(128) void sort_kernel(const int* __restrict__ samples,
                                                   unsigned short* __restrict__ cols) {
  const int row = blockIdx.x;
  const int t = threadIdx.x;
  __shared__ int s[NS];
  s[t] = samples[(size_t)row * NS + t];
  __syncthreads();

  for (unsigned k = 2; k <= NS; k <<= 1) {
    for (unsigned j = k >> 1; j > 0; j >>= 1) {
      const unsigned ixj = t ^ j;
      if (ixj > (unsigned)t) {
        const int a = s[t], b = s[ixj];
        const bool up = ((t & k) == 0);
        if ((up && a > b) || (!up && a < b)) { s[t] = b; s[ixj] = a; }
      }
      __syncthreads();
    }
  }

  cols[(size_t)row * NS + t] = (unsigned short)s[t];
}

// ---------------------------------------------------------------------------
// Attention: one block per (head, token). 128 threads. Writes O as bf16.
// ---------------------------------------------------------------------------
__global__ __launch_bounds__(128) void attn_kernel(const float* __restrict__ Q,
                                                   const float* __restrict__ Km,
                                                   const float* __restrict__ Vm,
                                                   const unsigned short* __restrict__ cols,
                                                   __hip_bfloat16* __restrict__ O) {
  const int h = blockIdx.x;
  const int i = blockIdx.y;
  const int t = threadIdx.x;

  __shared__ float q_s[HD];
  __shared__ int   c_s[NS];
  __shared__ float sc[NS];
  __shared__ float red[NS];
  __shared__ float part[2][HD];

  if (t < HD) q_s[t] = Q[(size_t)i * EMB + h * HD + t];
  const int c = (int)cols[(size_t)i * NS + t];
  c_s[t] = c;
  __syncthreads();
  const int dp = (t > 0 && c_s[t] == c_s[t - 1]) ? 1 : 0;

  // scores
  const float4* k4 = (const float4*)(Km + (size_t)c * EMB + h * HD);
  const float4* q4 = (const float4*)q_s;
  float acc = 0.f;
#pragma unroll
  for (int d4 = 0; d4 < HD / 4; d4++) {
    const float4 kv = k4[d4];
    const float4 qv = q4[d4];
    acc += qv.x * kv.x + qv.y * kv.y + qv.z * kv.z + qv.w * kv.w;
  }
  const float sval = dp ? -1e30f : acc * 0.03125f;  // 1/sqrt(1024)
  sc[t] = sval;
  red[t] = sval;
  __syncthreads();

  // max-reduce
  for (int off = 64; off > 0; off >>= 1) {
    if (t < off) red[t] = fmaxf(red[t], red[t + off]);
    __syncthreads();
  }
  const float m = red[0];
  __syncthreads();

  const float e = __expf(sc[t] - m);
  sc[t] = e;
  red[t] = e;
  __syncthreads();

  // sum-reduce
  for (int off = 64; off > 0; off >>= 1) {
    if (t < off) red[t] += red[t + off];
    __syncthreads();
  }
  const float inv = 1.0f / red[0];

  // PV: groups of 64 lanes, strided over samples
  const int d = t & 63;
  const int g = t >> 6;
  float o = 0.f;
  for (int s = g; s < NS; s += 2) {
    o += sc[s] * Vm[(size_t)c_s[s] * EMB + h * HD + d];
  }
  part[g][d] = o;
  __syncthreads();
  if (t < HD)
    O[(size_t)i * EMB + h * HD + t] = __float2bfloat16((part[0][t] + part[1][t]) * inv);
}

extern "C" void kernel_launch(void* const* d_in, const int* in_sizes, int n_in,
                              void* d_out, int out_size, void* d_ws, size_t ws_size,
                              hipStream_t stream) {
  const float* query = (const float*)d_in[0];
  const float* key   = (const float*)d_in[1];
  const float* value = (const float*)d_in[2];
  const float* Wq    = (const float*)d_in[3];
  const float* bq    = (const float*)d_in[4];
  const float* Wk    = (const float*)d_in[5];
  const float* bk    = (const float*)d_in[6];
  const float* Wv    = (const float*)d_in[7];
  const float* bv    = (const float*)d_in[8];
  const float* Wo    = (const float*)d_in[9];
  const float* bo    = (const float*)d_in[10];
  const int* samples = (const int*)d_in[11];
  float* out = (float*)d_out;

  // Workspace layout (14.25 MB total — stay well under ws_size):
  //   Q,K,V fp32: 3 * 4 MB; O bf16: 2 MB; cols u16: 0.25 MB
  float* Q = (float*)d_ws;
  float* K = Q + (size_t)NTOK * EMB;
  float* V = K + (size_t)NTOK * EMB;
  __hip_bfloat16* O = (__hip_bfloat16*)(V + (size_t)NTOK * EMB);
  unsigned short* cols = (unsigned short*)(O + (size_t)NTOK * EMB);

  const dim3 gg(16, 16), gb(256);
  gemm_nt<<<gg, gb, 0, stream>>>(query, Wq, bq, Q);
  gemm_nt<<<gg, gb, 0, stream>>>(key,   Wk, bk, K);
  gemm_nt<<<gg, gb, 0, stream>>>(value, Wv, bv, V);

  sort_kernel<<<NTOK, NS, 0, stream>>>(samples, cols);

  attn_kernel<<<dim3(NH, NTOK), NS, 0, stream>>>(Q, K, V, cols, O);

  gemm_nt_abf16<<<gg, gb, 0, stream>>>(O, Wo, bo, out);
}

// Round 3
// 156.150 us; speedup vs baseline: 2.5578x; 2.5578x over previous
//
#include <hip/hip_runtime.h>
#include <hip/hip_bf16.h>

#define NTOK 1024
#define EMB  1024
#define NH   16
#define HD   64
#define NS   128

typedef unsigned short u16;
typedef __attribute__((ext_vector_type(8))) short short8v;
typedef __attribute__((ext_vector_type(8))) unsigned short ushort8v;
typedef __attribute__((ext_vector_type(4))) float f32x4;

__device__ __forceinline__ u16 f2bf(float f) {
  union { float f; unsigned u; } x; x.f = f;
  return (u16)((x.u + 0x7FFFu + ((x.u >> 16) & 1u)) >> 16);
}
__device__ __forceinline__ float bf2f(u16 u) {
  union { unsigned u; float f; } x; x.u = ((unsigned)u) << 16;
  return x.f;
}

// ---------------------------------------------------------------------------
// C[M,N] = A[M,K] * B[N,K]^T + bias[N], M=N=K=1024.
// A: fp32 or bf16 (template). B: fp32 weights (converted in staging).
// 128x128 tile, BK=32, 256 threads (4 waves, 2x2 of 64x64 wave-tiles),
// mfma_f32_16x16x32_bf16, 4x4 fragments per wave.
// LDS row stride 56 elems = 112 B (odd multiple of 16 B: aligned b128 reads,
// 2-way bank rotation = free).
// blockIdx.z selects among three (A,B,bias) triples; C offset by z*1M elems.
// ---------------------------------------------------------------------------
template<bool A_BF16, bool OUT_BF16>
__global__ __launch_bounds__(256) void gemm_mfma(
    const void* __restrict__ A0, const void* __restrict__ A1, const void* __restrict__ A2,
    const float* __restrict__ B0, const float* __restrict__ B1, const float* __restrict__ B2,
    const float* __restrict__ b0, const float* __restrict__ b1, const float* __restrict__ b2,
    void* __restrict__ Cp) {
  __shared__ u16 As[128 * 56];
  __shared__ u16 Bs[128 * 56];

  const int t = threadIdx.x;
  const int lane = t & 63;
  const int w = t >> 6;
  const int wr = w >> 1, wc = w & 1;
  const int m0 = blockIdx.y * 128;
  const int n0 = blockIdx.x * 128;
  const int z = blockIdx.z;

  const void*  Asel = (z == 0) ? A0 : ((z == 1) ? A1 : A2);
  const float* Bsel = (z == 0) ? B0 : ((z == 1) ? B1 : B2);
  const float* bsel = (z == 0) ? b0 : ((z == 1) ? b1 : b2);

  const int srow = t >> 1;          // 0..127
  const int scol = (t & 1) * 16;    // 0 or 16

  f32x4 acc[4][4];
#pragma unroll
  for (int m = 0; m < 4; m++)
#pragma unroll
    for (int n = 0; n < 4; n++) acc[m][n] = (f32x4){0.f, 0.f, 0.f, 0.f};

  const int fr = lane & 15;
  const int fq = lane >> 4;
  const int kq = fq * 8;

  for (int k0 = 0; k0 < 1024; k0 += 32) {
    // ---- stage A tile (rows m0..m0+127, k k0..k0+31) ----
    if constexpr (A_BF16) {
      const u16* ap = (const u16*)Asel + (size_t)(m0 + srow) * 1024 + k0 + scol;
      *(ushort8v*)&As[srow * 56 + scol]     = ((const ushort8v*)ap)[0];
      *(ushort8v*)&As[srow * 56 + scol + 8] = ((const ushort8v*)ap)[1];
    } else {
      const float* ap = (const float*)Asel + (size_t)(m0 + srow) * 1024 + k0 + scol;
      const float4 f0 = ((const float4*)ap)[0];
      const float4 f1 = ((const float4*)ap)[1];
      const float4 f2 = ((const float4*)ap)[2];
      const float4 f3 = ((const float4*)ap)[3];
      ushort8v p0, p1;
      p0[0] = f2bf(f0.x); p0[1] = f2bf(f0.y); p0[2] = f2bf(f0.z); p0[3] = f2bf(f0.w);
      p0[4] = f2bf(f1.x); p0[5] = f2bf(f1.y); p0[6] = f2bf(f1.z); p0[7] = f2bf(f1.w);
      p1[0] = f2bf(f2.x); p1[1] = f2bf(f2.y); p1[2] = f2bf(f2.z); p1[3] = f2bf(f2.w);
      p1[4] = f2bf(f3.x); p1[5] = f2bf(f3.y); p1[6] = f2bf(f3.z); p1[7] = f2bf(f3.w);
      *(ushort8v*)&As[srow * 56 + scol]     = p0;
      *(ushort8v*)&As[srow * 56 + scol + 8] = p1;
    }
    // ---- stage B tile (weight rows n0..n0+127) ----
    {
      const float* bp = Bsel + (size_t)(n0 + srow) * 1024 + k0 + scol;
      const float4 f0 = ((const float4*)bp)[0];
      const float4 f1 = ((const float4*)bp)[1];
      const float4 f2 = ((const float4*)bp)[2];
      const float4 f3 = ((const float4*)bp)[3];
      ushort8v p0, p1;
      p0[0] = f2bf(f0.x); p0[1] = f2bf(f0.y); p0[2] = f2bf(f0.z); p0[3] = f2bf(f0.w);
      p0[4] = f2bf(f1.x); p0[5] = f2bf(f1.y); p0[6] = f2bf(f1.z); p0[7] = f2bf(f1.w);
      p1[0] = f2bf(f2.x); p1[1] = f2bf(f2.y); p1[2] = f2bf(f2.z); p1[3] = f2bf(f2.w);
      p1[4] = f2bf(f3.x); p1[5] = f2bf(f3.y); p1[6] = f2bf(f3.z); p1[7] = f2bf(f3.w);
      *(ushort8v*)&Bs[srow * 56 + scol]     = p0;
      *(ushort8v*)&Bs[srow * 56 + scol + 8] = p1;
    }
    __syncthreads();

    short8v a[4], b[4];
#pragma unroll
    for (int m = 0; m < 4; m++)
      a[m] = *(const short8v*)&As[(wr * 64 + m * 16 + fr) * 56 + kq];
#pragma unroll
    for (int n = 0; n < 4; n++)
      b[n] = *(const short8v*)&Bs[(wc * 64 + n * 16 + fr) * 56 + kq];
#pragma unroll
    for (int m = 0; m < 4; m++)
#pragma unroll
      for (int n = 0; n < 4; n++)
        acc[m][n] = __builtin_amdgcn_mfma_f32_16x16x32_bf16(a[m], b[n], acc[m][n], 0, 0, 0);
    __syncthreads();
  }

  // ---- epilogue: bias + store. C/D layout: col=lane&15, row=(lane>>4)*4+reg ----
  u16*   Cb = (u16*)Cp   + (size_t)z * 1024 * 1024;
  float* Cf = (float*)Cp + (size_t)z * 1024 * 1024;
#pragma unroll
  for (int n = 0; n < 4; n++) {
    const int col = n0 + wc * 64 + n * 16 + fr;
    const float bn = bsel[col];
#pragma unroll
    for (int m = 0; m < 4; m++) {
      const int rbase = m0 + wr * 64 + m * 16 + fq * 4;
#pragma unroll
      for (int r = 0; r < 4; r++) {
        const float val = acc[m][n][r] + bn;
        if constexpr (OUT_BF16)
          Cb[(size_t)(rbase + r) * 1024 + col] = f2bf(val);
        else
          Cf[(size_t)(rbase + r) * 1024 + col] = val;
      }
    }
  }
}

// ---------------------------------------------------------------------------
// Per-token bitonic sort of the 128 sample indices -> sorted u16 cols.
// ---------------------------------------------------------------------------
__global__ __launch_bounds__(128) void sort_kernel(const int* __restrict__ samples,
                                                   u16* __restrict__ cols) {
  const int row = blockIdx.x;
  const int t = threadIdx.x;
  __shared__ int s[NS];
  s[t] = samples[(size_t)row * NS + t];
  __syncthreads();

  for (unsigned k = 2; k <= NS; k <<= 1) {
    for (unsigned j = k >> 1; j > 0; j >>= 1) {
      const unsigned ixj = t ^ j;
      if (ixj > (unsigned)t) {
        const int a = s[t], b = s[ixj];
        const bool up = ((t & k) == 0);
        if ((up && a > b) || (!up && a < b)) { s[t] = b; s[ixj] = a; }
      }
      __syncthreads();
    }
  }
  cols[(size_t)row * NS + t] = (u16)s[t];
}

// ---------------------------------------------------------------------------
// Attention: ONE block per token, 256 threads (4 waves), all 16 heads.
//  score: thread t -> head h=t&15, sample-group sg=t>>4; q row in registers.
//  softmax: wave w handles heads 4w..4w+3, shuffle-reduce over 64 lanes.
//  PV: thread t -> head t>>4, dims (t&15)*4; coalesced 8B V loads.
// Q,K,V,O all bf16.
// ---------------------------------------------------------------------------
__global__ __launch_bounds__(256) void attn2(const u16* __restrict__ Qb,
                                             const u16* __restrict__ Kb,
                                             const u16* __restrict__ Vb,
                                             const u16* __restrict__ cols,
                                             u16* __restrict__ O) {
  const int i = blockIdx.x;
  const int t = threadIdx.x;

  __shared__ int   c_s[NS];
  __shared__ int   dup_s[NS];
  __shared__ float sc[16 * 132];   // padded: stride 132 floats

  if (t < NS) {
    const int c = (int)cols[(size_t)i * NS + t];
    c_s[t] = c;
    dup_s[t] = (t > 0 && c == (int)cols[(size_t)i * NS + t - 1]) ? 1 : 0;
  }
  __syncthreads();

  // ---- scores ----
  const int h = t & 15;
  const int sg = t >> 4;
  float q[64];
  {
    const u16* qp = Qb + (size_t)i * EMB + h * HD;
#pragma unroll
    for (int j = 0; j < 8; j++) {
      const ushort8v v = *(const ushort8v*)(qp + j * 8);
#pragma unroll
      for (int e = 0; e < 8; e++) q[j * 8 + e] = bf2f(v[e]);
    }
  }
#pragma unroll
  for (int r = 0; r < 8; r++) {
    const int s = sg + r * 16;
    const u16* kp = Kb + (size_t)c_s[s] * EMB + h * HD;
    float acc = 0.f;
#pragma unroll
    for (int j = 0; j < 8; j++) {
      const ushort8v kv = *(const ushort8v*)(kp + j * 8);
#pragma unroll
      for (int e = 0; e < 8; e++) acc += q[j * 8 + e] * bf2f(kv[e]);
    }
    sc[h * 132 + s] = dup_s[s] ? -1e30f : acc * 0.03125f;  // 1/sqrt(1024)
  }
  __syncthreads();

  // ---- per-head softmax (wave-parallel) ----
  const int wv = t >> 6, l = t & 63;
#pragma unroll
  for (int hh0 = 0; hh0 < 4; hh0++) {
    const int hh = wv * 4 + hh0;
    const float x0 = sc[hh * 132 + l];
    const float x1 = sc[hh * 132 + 64 + l];
    float mx = fmaxf(x0, x1);
#pragma unroll
    for (int off = 32; off > 0; off >>= 1) mx = fmaxf(mx, __shfl_xor(mx, off, 64));
    const float e0 = __expf(x0 - mx);
    const float e1 = __expf(x1 - mx);
    float sm = e0 + e1;
#pragma unroll
    for (int off = 32; off > 0; off >>= 1) sm += __shfl_xor(sm, off, 64);
    const float inv = 1.0f / sm;
    sc[hh * 132 + l]      = e0 * inv;
    sc[hh * 132 + 64 + l] = e1 * inv;
  }
  __syncthreads();

  // ---- PV ----
  const int ph = t >> 4;
  const int g = ph * HD + (t & 15) * 4;   // global dim, float4-of-bf16 per thread
  float ox = 0.f, oy = 0.f, oz = 0.f, ow = 0.f;
#pragma unroll 4
  for (int s = 0; s < NS; s++) {
    const float wgt = sc[ph * 132 + s];
    const ushort4 v = *(const ushort4*)(Vb + (size_t)c_s[s] * EMB + g);
    ox += wgt * bf2f(v.x);
    oy += wgt * bf2f(v.y);
    oz += wgt * bf2f(v.z);
    ow += wgt * bf2f(v.w);
  }
  ushort4 ov;
  ov.x = f2bf(ox); ov.y = f2bf(oy); ov.z = f2bf(oz); ov.w = f2bf(ow);
  *(ushort4*)(O + (size_t)i * EMB + g) = ov;
}

extern "C" void kernel_launch(void* const* d_in, const int* in_sizes, int n_in,
                              void* d_out, int out_size, void* d_ws, size_t ws_size,
                              hipStream_t stream) {
  const float* query = (const float*)d_in[0];
  const float* key   = (const float*)d_in[1];
  const float* value = (const float*)d_in[2];
  const float* Wq    = (const float*)d_in[3];
  const float* bq    = (const float*)d_in[4];
  const float* Wk    = (const float*)d_in[5];
  const float* bk    = (const float*)d_in[6];
  const float* Wv    = (const float*)d_in[7];
  const float* bv    = (const float*)d_in[8];
  const float* Wo    = (const float*)d_in[9];
  const float* bo    = (const float*)d_in[10];
  const int* samples = (const int*)d_in[11];
  float* out = (float*)d_out;

  // ws layout (bf16): Qb,Kb,Vb 3*2MB; O 2MB; cols 0.25MB  => 8.25 MB total
  u16* Qb = (u16*)d_ws;
  u16* Kb = Qb + (size_t)NTOK * EMB;
  u16* Vb = Kb + (size_t)NTOK * EMB;
  u16* O  = Vb + (size_t)NTOK * EMB;
  u16* cols = O + (size_t)NTOK * EMB;

  // fused QKV projections (z = 0,1,2)
  gemm_mfma<false, true><<<dim3(8, 8, 3), 256, 0, stream>>>(
      query, key, value, Wq, Wk, Wv, bq, bk, bv, Qb);

  sort_kernel<<<NTOK, NS, 0, stream>>>(samples, cols);

  attn2<<<NTOK, 256, 0, stream>>>(Qb, Kb, Vb, cols, O);

  // output projection (A = O bf16, out fp32)
  gemm_mfma<true, false><<<dim3(8, 8, 1), 256, 0, stream>>>(
      O, O, O, Wo, Wo, Wo, bo, bo, bo, out);
}